// Round 9
// baseline (165.590 us; speedup 1.0000x reference)
//
#include <hip/hip_runtime.h>

// popcount of ballot bits strictly below this lane (wave64)
__device__ __forceinline__ int lanes_below(unsigned long long m) {
    return __builtin_amdgcn_mbcnt_hi((unsigned)(m >> 32),
           __builtin_amdgcn_mbcnt_lo((unsigned)m, 0u));
}

// Workspace layout (zeroed by hipMemsetAsync each call):
//   float gslot[64];     // per-group partial sums (atomicAdd, <=64 adds each)
//   unsigned gcnt[64];   // per-group completion counters (<=64 adds each)
//   unsigned fin_cnt;    // final counter (<=64 adds)
#define WS_GSLOT(ws)  ((float*)(ws))
#define WS_GCNT(ws)   ((unsigned*)((char*)(ws) + 64 * sizeof(float)))
#define WS_FINCNT(ws) ((unsigned*)((char*)(ws) + 64 * sizeof(float) + 64 * sizeof(unsigned)))

// Masked MSE with ragged alignment — one 512-thread block per row (max TLP),
// R5 branch-free inner path, fused epilogue via two-level atomic finisher
// (max 64 RMWs per address — R6 showed 4096-way single-address = +38us).
__global__ __launch_bounds__(512, 8) void masked_mse_rows(
    const float* __restrict__ pred,
    const float* __restrict__ target,
    const int*   __restrict__ mask,
    float*       __restrict__ gslot,
    unsigned*    __restrict__ gcnt,
    unsigned*    __restrict__ fin_cnt,
    float*       __restrict__ out,
    int S, int B)
{
    const int tid  = threadIdx.x;
    const int lane = tid & 63;
    const int wid  = tid >> 6;          // 0..7
    const int row  = blockIdx.x;

    const float4* __restrict__ p4 = reinterpret_cast<const float4*>(pred + (size_t)row * S);
    const int4*   __restrict__ m4 = reinterpret_cast<const int4*>(mask + (size_t)row * S);
    const float*  __restrict__ trow = target + (size_t)row * S;

    // all four big loads independent, issued together
    const int4   ma = m4[tid];
    const int4   mb = m4[tid + 512];
    const float4 pa = p4[tid];
    const float4 pb = p4[tid + 512];

    const int c0 = (ma.x != 0), c1 = (ma.y != 0), c2 = (ma.z != 0), c3 = (ma.w != 0);
    const int c4 = (mb.x != 0), c5 = (mb.y != 0), c6 = (mb.z != 0), c7 = (mb.w != 0);

    const unsigned long long a0 = __ballot(c0);
    const unsigned long long a1 = __ballot(c1);
    const unsigned long long a2 = __ballot(c2);
    const unsigned long long a3 = __ballot(c3);
    const unsigned long long b0 = __ballot(c4);
    const unsigned long long b1 = __ballot(c5);
    const unsigned long long b2 = __ballot(c6);
    const unsigned long long b3 = __ballot(c7);

    const int pref_a = lanes_below(a0) + lanes_below(a1) + lanes_below(a2) + lanes_below(a3);
    const int pref_b = lanes_below(b0) + lanes_below(b1) + lanes_below(b2) + lanes_below(b3);
    const int tot_a  = __popcll(a0) + __popcll(a1) + __popcll(a2) + __popcll(a3);
    const int tot_b  = __popcll(b0) + __popcll(b1) + __popcll(b2) + __popcll(b3);

    __shared__ int   tsum[16];
    __shared__ float facc[8];
    __shared__ int   flags[2];   // [0]=isGroupFin, [1]=isFinal

    if (lane == 0) { tsum[wid] = tot_a; tsum[8 + wid] = tot_b; }
    __syncthreads();

    int base_a = 0, pre_b = 0, sumA = 0;
    #pragma unroll
    for (int w = 0; w < 8; ++w) {
        const int va = tsum[w], vb = tsum[8 + w];
        base_a += (w < wid) ? va : 0;
        pre_b  += (w < wid) ? vb : 0;
        sumA   += va;
    }
    const int base_b = sumA + pre_b;

    // branch-free: all 8 gather addresses first (pure VALU chain)
    int idx[8];
    {
        int r = base_a + pref_a;
        idx[0] = r; r += c0;
        idx[1] = r; r += c1;
        idx[2] = r; r += c2;
        idx[3] = r; r += c3;
    }
    {
        int r = base_b + pref_b;
        idx[4] = r; r += c4;
        idx[5] = r; r += c5;
        idx[6] = r; r += c6;
        idx[7] = r; r += c7;
    }
    float tv[8];
    #pragma unroll
    for (int j = 0; j < 8; ++j) tv[j] = trow[idx[j]];   // 8 independent loads

    const float pv[8] = {pa.x, pa.y, pa.z, pa.w, pb.x, pb.y, pb.z, pb.w};
    const int   cs[8] = {c0, c1, c2, c3, c4, c5, c6, c7};
    float acc = 0.0f;
    #pragma unroll
    for (int j = 0; j < 8; ++j) {
        const float d = pv[j] - tv[j];
        acc += cs[j] ? d * d : 0.0f;
    }

    // wave reduce, then cross-wave via LDS
    #pragma unroll
    for (int off = 32; off > 0; off >>= 1) acc += __shfl_down(acc, off, 64);
    if (lane == 0) facc[wid] = acc;
    __syncthreads();

    // ---- fused epilogue: two-level atomic finisher ----
    const int g = blockIdx.x & 63;                       // group id (spread in dispatch order)
    if (tid == 0) {
        float s = 0.0f;
        #pragma unroll
        for (int w = 0; w < 8; ++w) s += facc[w];
        atomicAdd(&gslot[g], s);
        __threadfence();                                 // order gslot add before gcnt add
        const unsigned members = (unsigned)(B >> 6) + ((unsigned)(B & 63) > (unsigned)g ? 1u : 0u);
        const unsigned old = atomicAdd(&gcnt[g], 1u);
        flags[0] = (old == members - 1u);
    }
    __syncthreads();
    if (flags[0]) {                                      // this block finished its group
        if (tid == 0) {
            __threadfence();
            const unsigned ngroups = (unsigned)((B < 64) ? B : 64);
            const unsigned w = atomicAdd(fin_cnt, 1u);
            flags[1] = (w == ngroups - 1u);
        }
        __syncthreads();
        if (flags[1] && wid == 0) {                      // last group: wave 0 sums 64 slots
            const int ngroups = (B < 64) ? B : 64;
            float v = (lane < ngroups) ? atomicAdd(&gslot[lane], 0.0f) : 0.0f; // coherent read
            #pragma unroll
            for (int off = 32; off > 0; off >>= 1) v += __shfl_down(v, off, 64);
            if (lane == 0) out[0] = v;
        }
    }
}

extern "C" void kernel_launch(void* const* d_in, const int* in_sizes, int n_in,
                              void* d_out, int out_size, void* d_ws, size_t ws_size,
                              hipStream_t stream) {
    const float* pred   = (const float*)d_in[0];
    const float* target = (const float*)d_in[1];
    const int*   mask   = (const int*)d_in[2];
    float* out = (float*)d_out;

    const int S = 4096;
    const int B = in_sizes[0] / S;

    // zero the 516-byte finisher workspace (handles 0xAA poison + replay reset)
    hipMemsetAsync(d_ws, 0, 64 * sizeof(float) + 65 * sizeof(unsigned), stream);

    masked_mse_rows<<<B, 512, 0, stream>>>(
        pred, target, mask,
        WS_GSLOT(d_ws), WS_GCNT(d_ws), WS_FINCNT(d_ws),
        out, S, B);
}

// Round 10
// 33.399 us; speedup vs baseline: 4.9580x; 4.9580x over previous
//
#include <hip/hip_runtime.h>

// popcount of ballot bits strictly below this lane (wave64)
__device__ __forceinline__ int lanes_below(unsigned long long m) {
    return __builtin_amdgcn_mbcnt_hi((unsigned)(m >> 32),
           __builtin_amdgcn_mbcnt_lo((unsigned)m, 0u));
}

// Masked MSE with ragged alignment — one 512-thread block per row (max TLP),
// branch-free gather, ONE barrier per block. Each wave writes its own partial
// to wave_sums[row*8+wid] (no cross-wave LDS reduce, no atomics — R6/R8/R9
// showed all cross-block coordination schemes cost 2-5x).
__global__ __launch_bounds__(512, 8) void masked_mse_rows(
    const float* __restrict__ pred,
    const float* __restrict__ target,
    const int*   __restrict__ mask,
    float*       __restrict__ wave_sums,
    int S)
{
    const int tid  = threadIdx.x;
    const int lane = tid & 63;
    const int wid  = tid >> 6;          // 0..7
    const int row  = blockIdx.x;

    const float4* __restrict__ p4 = reinterpret_cast<const float4*>(pred + (size_t)row * S);
    const int4*   __restrict__ m4 = reinterpret_cast<const int4*>(mask + (size_t)row * S);
    const float*  __restrict__ trow = target + (size_t)row * S;

    // all four big loads independent, issued together
    const int4   ma = m4[tid];
    const int4   mb = m4[tid + 512];
    const float4 pa = p4[tid];
    const float4 pb = p4[tid + 512];

    const int c0 = (ma.x != 0), c1 = (ma.y != 0), c2 = (ma.z != 0), c3 = (ma.w != 0);
    const int c4 = (mb.x != 0), c5 = (mb.y != 0), c6 = (mb.z != 0), c7 = (mb.w != 0);

    const unsigned long long a0 = __ballot(c0);
    const unsigned long long a1 = __ballot(c1);
    const unsigned long long a2 = __ballot(c2);
    const unsigned long long a3 = __ballot(c3);
    const unsigned long long b0 = __ballot(c4);
    const unsigned long long b1 = __ballot(c5);
    const unsigned long long b2 = __ballot(c6);
    const unsigned long long b3 = __ballot(c7);

    const int pref_a = lanes_below(a0) + lanes_below(a1) + lanes_below(a2) + lanes_below(a3);
    const int pref_b = lanes_below(b0) + lanes_below(b1) + lanes_below(b2) + lanes_below(b3);
    const int tot_a  = __popcll(a0) + __popcll(a1) + __popcll(a2) + __popcll(a3);
    const int tot_b  = __popcll(b0) + __popcll(b1) + __popcll(b2) + __popcll(b3);

    __shared__ int tsum[16];
    if (lane == 0) { tsum[wid] = tot_a; tsum[8 + wid] = tot_b; }
    __syncthreads();                     // the ONLY barrier in this kernel

    int base_a = 0, pre_b = 0, sumA = 0;
    #pragma unroll
    for (int w = 0; w < 8; ++w) {
        const int va = tsum[w], vb = tsum[8 + w];
        base_a += (w < wid) ? va : 0;
        pre_b  += (w < wid) ? vb : 0;
        sumA   += va;
    }
    const int base_b = sumA + pre_b;

    // branch-free: all 8 gather addresses first (pure VALU chain)
    int idx[8];
    {
        int r = base_a + pref_a;
        idx[0] = r; r += c0;
        idx[1] = r; r += c1;
        idx[2] = r; r += c2;
        idx[3] = r; r += c3;
    }
    {
        int r = base_b + pref_b;
        idx[4] = r; r += c4;
        idx[5] = r; r += c5;
        idx[6] = r; r += c6;
        idx[7] = r; r += c7;
    }
    float tv[8];
    #pragma unroll
    for (int j = 0; j < 8; ++j) tv[j] = trow[idx[j]];   // 8 independent loads

    const float pv[8] = {pa.x, pa.y, pa.z, pa.w, pb.x, pb.y, pb.z, pb.w};
    const int   cs[8] = {c0, c1, c2, c3, c4, c5, c6, c7};
    float acc = 0.0f;
    #pragma unroll
    for (int j = 0; j < 8; ++j) {
        const float d = pv[j] - tv[j];
        acc += cs[j] ? d * d : 0.0f;
    }

    // wave reduce; lane 0 writes this wave's partial (no cross-wave reduce)
    #pragma unroll
    for (int off = 32; off > 0; off >>= 1) acc += __shfl_down(acc, off, 64);
    if (lane == 0) wave_sums[row * 8 + wid] = acc;
}

// Deterministic final reduce of B*8 wave partials into d_out[0].
__global__ __launch_bounds__(1024) void reduce_waves(
    const float* __restrict__ wave_sums, float* __restrict__ out, int n)
{
    const int tid = threadIdx.x;
    float acc = 0.0f;
    const int n4 = n >> 2;
    const float4* ws4 = reinterpret_cast<const float4*>(wave_sums);
    for (int i = tid; i < n4; i += 1024) {
        float4 v = ws4[i];
        acc += (v.x + v.y) + (v.z + v.w);
    }
    for (int i = (n4 << 2) + tid; i < n; i += 1024) acc += wave_sums[i];

    #pragma unroll
    for (int off = 32; off > 0; off >>= 1) acc += __shfl_down(acc, off, 64);
    __shared__ float facc[16];
    if ((tid & 63) == 0) facc[tid >> 6] = acc;
    __syncthreads();
    if (tid == 0) {
        float s = 0.0f;
        #pragma unroll
        for (int w = 0; w < 16; ++w) s += facc[w];
        out[0] = s;
    }
}

extern "C" void kernel_launch(void* const* d_in, const int* in_sizes, int n_in,
                              void* d_out, int out_size, void* d_ws, size_t ws_size,
                              hipStream_t stream) {
    const float* pred   = (const float*)d_in[0];
    const float* target = (const float*)d_in[1];
    const int*   mask   = (const int*)d_in[2];
    float* out = (float*)d_out;
    float* wave_sums = (float*)d_ws;

    const int S = 4096;
    const int B = in_sizes[0] / S;

    masked_mse_rows<<<B, 512, 0, stream>>>(pred, target, mask, wave_sums, S);
    reduce_waves<<<1, 1024, 0, stream>>>(wave_sums, out, B * 8);
}

// Round 11
// 31.210 us; speedup vs baseline: 5.3056x; 1.0701x over previous
//
#include <hip/hip_runtime.h>

// popcount of ballot bits strictly below this lane (wave64)
__device__ __forceinline__ int lanes_below(unsigned long long m) {
    return __builtin_amdgcn_mbcnt_hi((unsigned)(m >> 32),
           __builtin_amdgcn_mbcnt_lo((unsigned)m, 0u));
}

// Masked MSE with ragged alignment — one 512-thread block per row, single-shot,
// branch-free gather. Best-measured configuration (R5: 31.2 us).
// Session findings baked in:
//  - max TLP (4096 independent blocks) beats all row-looping structures (R8)
//  - branch-free gather (addresses via pure VALU, 8 independent loads) beats
//    exec-masked serial gather by ~4 us (R4->R5)
//  - LDS compaction of pred ties this (R7); scattered gather is no worse
//  - ANY cross-block fused epilogue loses big: single-address atomic +38us
//    (R6), grid.sync +70us (R8), two-level finisher+fence +134us (R9)
//  - dropping the cross-wave reduce/barrier regresses ~2us (R10)
__global__ __launch_bounds__(512, 8) void masked_mse_rows(
    const float* __restrict__ pred,
    const float* __restrict__ target,
    const int*   __restrict__ mask,
    float*       __restrict__ row_sums,
    int S)
{
    const int tid  = threadIdx.x;
    const int lane = tid & 63;
    const int wid  = tid >> 6;          // 0..7
    const int row  = blockIdx.x;

    const float4* __restrict__ p4 = reinterpret_cast<const float4*>(pred + (size_t)row * S);
    const int4*   __restrict__ m4 = reinterpret_cast<const int4*>(mask + (size_t)row * S);
    const float*  __restrict__ trow = target + (size_t)row * S;

    // all four big loads independent, issued together
    const int4   ma = m4[tid];
    const int4   mb = m4[tid + 512];
    const float4 pa = p4[tid];
    const float4 pb = p4[tid + 512];

    const int c0 = (ma.x != 0), c1 = (ma.y != 0), c2 = (ma.z != 0), c3 = (ma.w != 0);
    const int c4 = (mb.x != 0), c5 = (mb.y != 0), c6 = (mb.z != 0), c7 = (mb.w != 0);

    // ballots per element slot, lane-prefix via mbcnt (pure VALU, no scan chain)
    const unsigned long long a0 = __ballot(c0);
    const unsigned long long a1 = __ballot(c1);
    const unsigned long long a2 = __ballot(c2);
    const unsigned long long a3 = __ballot(c3);
    const unsigned long long b0 = __ballot(c4);
    const unsigned long long b1 = __ballot(c5);
    const unsigned long long b2 = __ballot(c6);
    const unsigned long long b3 = __ballot(c7);

    const int pref_a = lanes_below(a0) + lanes_below(a1) + lanes_below(a2) + lanes_below(a3);
    const int pref_b = lanes_below(b0) + lanes_below(b1) + lanes_below(b2) + lanes_below(b3);
    const int tot_a  = __popcll(a0) + __popcll(a1) + __popcll(a2) + __popcll(a3); // wave-uniform
    const int tot_b  = __popcll(b0) + __popcll(b1) + __popcll(b2) + __popcll(b3);

    __shared__ int   tsum[16];
    __shared__ float facc[8];
    if (lane == 0) { tsum[wid] = tot_a; tsum[8 + wid] = tot_b; }
    __syncthreads();

    int base_a = 0, pre_b = 0, sumA = 0;
    #pragma unroll
    for (int w = 0; w < 8; ++w) {
        const int va = tsum[w], vb = tsum[8 + w];
        base_a += (w < wid) ? va : 0;
        pre_b  += (w < wid) ? vb : 0;
        sumA   += va;
    }
    const int base_b = sumA + pre_b;

    // ---- branch-free: all 8 gather addresses first (pure VALU chain) ----
    int idx[8];
    {
        int r = base_a + pref_a;
        idx[0] = r; r += c0;
        idx[1] = r; r += c1;
        idx[2] = r; r += c2;
        idx[3] = r; r += c3;
    }
    {
        int r = base_b + pref_b;
        idx[4] = r; r += c4;
        idx[5] = r; r += c5;
        idx[6] = r; r += c6;
        idx[7] = r; r += c7;
    }
    // addresses are provably <= S-1, so unconditional loads are in-bounds.
    float tv[8];
    #pragma unroll
    for (int j = 0; j < 8; ++j) tv[j] = trow[idx[j]];   // 8 independent loads

    const float pv[8] = {pa.x, pa.y, pa.z, pa.w, pb.x, pb.y, pb.z, pb.w};
    const int   cs[8] = {c0, c1, c2, c3, c4, c5, c6, c7};
    float acc = 0.0f;
    #pragma unroll
    for (int j = 0; j < 8; ++j) {
        const float d = pv[j] - tv[j];
        acc += cs[j] ? d * d : 0.0f;
    }

    // wave reduce, then cross-wave via LDS
    #pragma unroll
    for (int off = 32; off > 0; off >>= 1) acc += __shfl_down(acc, off, 64);
    if (lane == 0) facc[wid] = acc;
    __syncthreads();
    if (tid == 0) {
        float s = 0.0f;
        #pragma unroll
        for (int w = 0; w < 8; ++w) s += facc[w];
        row_sums[row] = s;
    }
}

// Deterministic final reduce of B row partials into d_out[0].
__global__ __launch_bounds__(1024) void reduce_rows(
    const float* __restrict__ row_sums, float* __restrict__ out, int n)
{
    const int tid = threadIdx.x;
    float acc = 0.0f;
    const int n4 = n >> 2;
    const float4* rs4 = reinterpret_cast<const float4*>(row_sums);
    for (int i = tid; i < n4; i += 1024) {
        float4 v = rs4[i];
        acc += (v.x + v.y) + (v.z + v.w);
    }
    for (int i = (n4 << 2) + tid; i < n; i += 1024) acc += row_sums[i];

    #pragma unroll
    for (int off = 32; off > 0; off >>= 1) acc += __shfl_down(acc, off, 64);
    __shared__ float facc[16];
    if ((tid & 63) == 0) facc[tid >> 6] = acc;
    __syncthreads();
    if (tid == 0) {
        float s = 0.0f;
        #pragma unroll
        for (int w = 0; w < 16; ++w) s += facc[w];
        out[0] = s;
    }
}

extern "C" void kernel_launch(void* const* d_in, const int* in_sizes, int n_in,
                              void* d_out, int out_size, void* d_ws, size_t ws_size,
                              hipStream_t stream) {
    const float* pred   = (const float*)d_in[0];
    const float* target = (const float*)d_in[1];
    const int*   mask   = (const int*)d_in[2];
    float* out = (float*)d_out;
    float* row_sums = (float*)d_ws;

    const int S = 4096;
    const int B = in_sizes[0] / S;

    masked_mse_rows<<<B, 512, 0, stream>>>(pred, target, mask, row_sums, S);
    reduce_rows<<<1, 1024, 0, stream>>>(row_sums, out, B);
}